// Round 8
// baseline (279.070 us; speedup 1.0000x reference)
//
#include <hip/hip_runtime.h>
#include <stdint.h>

#define K_DIM 4096
#define N_DIM 11008
#define WORDS_N 1376          // N_DIM / 8 packed words
#define BM 128
#define BN 256
#define BK 64
#define ASTR 72               // As row stride in fp16 elems (144B; even bank spread for b128)
#define WSTR 68               // Wq row stride in ints (272B: 16B-aligned, bank-spread)

typedef _Float16 f16x2 __attribute__((ext_vector_type(2)));
typedef _Float16 f16x8 __attribute__((ext_vector_type(8)));
typedef float    f32x4 __attribute__((ext_vector_type(4)));
typedef float    f32x8 __attribute__((ext_vector_type(8)));
typedef int      int4v __attribute__((ext_vector_type(4)));
typedef unsigned short ushort;
typedef unsigned int u32;

// two packed-word k-values -> half2 of dequantized weights for one column
// (q-z)*s via pk_fma(q, s, -zs); q built exactly via 0x6400 magic + pk_sub(1024)
__device__ __forceinline__ f16x2 dq2(int wa, int wb, int shf, f16x2 s2, f16x2 c2) {
    u32 t0 = ((u32)wa >> shf) & 0xFu;
    u32 t1 = ((u32)wb >> shf) & 0xFu;
    u32 h  = 0x64006400u | t0 | (t1 << 16);
    f16x2 q = __builtin_bit_cast(f16x2, h);
    q = q - (f16x2)((_Float16)1024.0f);   // exact: (1024+q) - 1024
    return q * s2 + c2;                    // v_pk_fma_f16
}

// ---- pre-pass: x f32 -> fp16 (values are exactly fp16-representable) ----
__global__ __launch_bounds__(256)
void cvt_x_kernel(const float* __restrict__ x, ushort* __restrict__ xf, int n8) {
    for (int i = blockIdx.x * 256 + threadIdx.x; i < n8; i += gridDim.x * 256) {
        f32x4 a = *(const f32x4*)(x + (size_t)i * 8);
        f32x4 b = *(const f32x4*)(x + (size_t)i * 8 + 4);
        int4v o;
        o[0] = __builtin_bit_cast(int, __builtin_amdgcn_cvt_pkrtz(a[0], a[1]));
        o[1] = __builtin_bit_cast(int, __builtin_amdgcn_cvt_pkrtz(a[2], a[3]));
        o[2] = __builtin_bit_cast(int, __builtin_amdgcn_cvt_pkrtz(b[0], b[1]));
        o[3] = __builtin_bit_cast(int, __builtin_amdgcn_cvt_pkrtz(b[2], b[3]));
        *(int4v*)(xf + (size_t)i * 8) = o;
    }
}

template <bool XF16>
__global__ __launch_bounds__(256, 2)
void awq_gemm_kernel(const void* __restrict__ xin,
                     const int* __restrict__ qw,
                     const int* __restrict__ qz,
                     const float* __restrict__ sc,
                     const float* __restrict__ bias,
                     float* __restrict__ out,
                     int M)
{
    // double-buffered tiles: write buf^1 while computing buf (one barrier/iter)
    __shared__ __align__(16) _Float16 As[2][BM * ASTR];  // 2 x 18432 B
    __shared__ __align__(16) int Wq[2][32 * WSTR];       // 2 x 8704 B

    const int tid  = threadIdx.x;
    const int lane = tid & 63;
    const int wid  = tid >> 6;

    const int bn0 = blockIdx.x * BN;
    const int bm0 = blockIdx.y * BM;
    const int w0  = bn0 >> 3;            // first packed word col of this tile (32 words)

    // 1x4 wave grid: each wave owns all 128 rows x 64 distinct cols
    const int wn0 = wid * 64;

    // A staging: 4 rows of 8 fp16 (or 8 f32) per thread
    const int a_row = tid >> 3;          // 0..31 (+32*i)
    const int a_col = (tid & 7) * 8;

    // B raw staging: each thread two dwordx4 (words b_wg..+3 and b_wg+16..+19, one k-row)
    const int b_krow = tid >> 2;         // 0..63
    const int b_wg   = (tid & 3) * 4;    // 0,4,8,12

    // per-bn column constants (AWQ interleave vs ORDER_SHIFTS verified)
    int n_loc[4], w_loc[4], shf[4];
    #pragma unroll
    for (int bn = 0; bn < 4; ++bn) {
        n_loc[bn] = wn0 + bn * 16 + (lane & 15);     // 0..255 within block
        w_loc[bn] = n_loc[bn] >> 3;                  // 0..31
        int j = n_loc[bn] & 7;
        shf[bn] = ((j & 1) << 4) + ((j >> 1) << 2);  // j -> [0,16,4,20,8,24,12,28]
    }

    f16x2 s2[4], c2[4];   // scale and -(z*s) per owned column

    f32x4 acc[8][4];
    #pragma unroll
    for (int i = 0; i < 8; ++i)
        #pragma unroll
        for (int j = 0; j < 4; ++j)
            acc[i][j] = (f32x4){0.f, 0.f, 0.f, 0.f};

    int4v aReg16[4];
    f32x8 aReg32[4];
    int4v bReg[2];

    const ushort* x16 = (const ushort*)xin;
    const float*  x32 = (const float*)xin;

#define LOAD_TILE(K0)                                                                  \
    {                                                                                  \
        _Pragma("unroll")                                                              \
        for (int i = 0; i < 4; ++i) {                                                  \
            int row = bm0 + a_row + i * 32;                                            \
            if constexpr (XF16) {                                                      \
                if (row < M)                                                           \
                    aReg16[i] = *(const int4v*)(x16 + (size_t)row * K_DIM + (K0) + a_col); \
                else                                                                   \
                    aReg16[i] = (int4v){0, 0, 0, 0};                                   \
            } else {                                                                   \
                if (row < M)                                                           \
                    aReg32[i] = *(const f32x8*)(x32 + (size_t)row * K_DIM + (K0) + a_col); \
                else                                                                   \
                    aReg32[i] = (f32x8){0.f,0.f,0.f,0.f,0.f,0.f,0.f,0.f};              \
            }                                                                          \
        }                                                                              \
        bReg[0] = *(const int4v*)(qw + (size_t)((K0) + b_krow) * WORDS_N + w0 + b_wg);      \
        bReg[1] = *(const int4v*)(qw + (size_t)((K0) + b_krow) * WORDS_N + w0 + b_wg + 16); \
    }

#define WRITE_TILE(BUF)                                                                \
    {                                                                                  \
        _Pragma("unroll")                                                              \
        for (int i = 0; i < 4; ++i) {                                                  \
            if constexpr (XF16) {                                                      \
                *(int4v*)&As[BUF][(a_row + i * 32) * ASTR + a_col] = aReg16[i];        \
            } else {                                                                   \
                f16x8 h;                                                               \
                _Pragma("unroll")                                                      \
                for (int r = 0; r < 4; ++r) {                                          \
                    f16x2 p = __builtin_bit_cast(f16x2,                                \
                        __builtin_amdgcn_cvt_pkrtz(aReg32[i][2*r], aReg32[i][2*r+1])); \
                    h[2*r]   = p[0];                                                   \
                    h[2*r+1] = p[1];                                                   \
                }                                                                      \
                *(f16x8*)&As[BUF][(a_row + i * 32) * ASTR + a_col] = h;                \
            }                                                                          \
        }                                                                              \
        _Pragma("unroll")                                                              \
        for (int c = 0; c < 4; ++c) {                                                  \
            Wq[BUF][(b_wg + c) * WSTR + b_krow]      = bReg[0][c];                     \
            Wq[BUF][(b_wg + 16 + c) * WSTR + b_krow] = bReg[1][c];                     \
        }                                                                              \
    }

    const int NT = K_DIM / BK;  // 64

    // prologue: stage tile 0, start tile-1 loads
    LOAD_TILE(0);
    WRITE_TILE(0);
    LOAD_TILE(BK);
    __syncthreads();

    int cur = 0;
    for (int t = 0; t < NT; ++t) {
        // stage tile t+1 into the other buffer (regs hold it; vmcnt wait implicit),
        // then kick off tile t+2 global loads — both overlap this iter's compute.
        if (t + 1 < NT) {
            WRITE_TILE(cur ^ 1);
            if (t + 2 < NT) LOAD_TILE((t + 2) * BK);
        }

        if ((t & 1) == 0) {   // group changes every 2 tiles (GROUP=128, BK=64)
            const int g = (t * BK) >> 7;
            #pragma unroll
            for (int bn = 0; bn < 4; ++bn) {
                float s = sc[(size_t)g * N_DIM + bn0 + n_loc[bn]];
                int zq  = (qz[(size_t)g * WORDS_N + w0 + w_loc[bn]] >> shf[bn]) & 0xF;
                _Float16 sh = (_Float16)s;
                _Float16 nz = (_Float16)(-(float)zq * s);
                s2[bn] = (f16x2){sh, sh};
                c2[bn] = (f16x2){nz, nz};
            }
        }

        const _Float16* asP = As[cur];
        const int*      wqP = Wq[cur];

        __builtin_amdgcn_s_setprio(1);
        #pragma unroll
        for (int ks = 0; ks < 2; ++ks) {
            const int kk = ks * 32 + (lane >> 4) * 8;   // this lane's k-octet
            f16x8 af[8];
            #pragma unroll
            for (int am = 0; am < 8; ++am)
                af[am] = *(const f16x8*)&asP[(am * 16 + (lane & 15)) * ASTR + kk];

            #pragma unroll
            for (int bn = 0; bn < 4; ++bn) {
                const int4v lo = *(const int4v*)&wqP[w_loc[bn] * WSTR + kk];
                const int4v hi = *(const int4v*)&wqP[w_loc[bn] * WSTR + kk + 4];
                f16x8 bf;
                f16x2 p;
                p = dq2(lo[0], lo[1], shf[bn], s2[bn], c2[bn]); bf[0]=p[0]; bf[1]=p[1];
                p = dq2(lo[2], lo[3], shf[bn], s2[bn], c2[bn]); bf[2]=p[0]; bf[3]=p[1];
                p = dq2(hi[0], hi[1], shf[bn], s2[bn], c2[bn]); bf[4]=p[0]; bf[5]=p[1];
                p = dq2(hi[2], hi[3], shf[bn], s2[bn], c2[bn]); bf[6]=p[0]; bf[7]=p[1];
                #pragma unroll
                for (int am = 0; am < 8; ++am)
                    acc[am][bn] = __builtin_amdgcn_mfma_f32_16x16x32_f16(
                        af[am], bf, acc[am][bn], 0, 0, 0);
            }
        }
        __builtin_amdgcn_s_setprio(0);

        if (t + 1 < NT) __syncthreads();   // buf[cur] free to overwrite; buf[cur^1] visible
        cur ^= 1;
    }

    // epilogue: C/D layout col=lane&15, row=(lane>>4)*4+r (m89-verified)
    #pragma unroll
    for (int bn = 0; bn < 4; ++bn) {
        const int col = bn0 + wn0 + bn * 16 + (lane & 15);
        const float b_f = bias[col];
        #pragma unroll
        for (int am = 0; am < 8; ++am) {
            const int row_base = bm0 + am * 16 + ((lane >> 4) << 2);
            #pragma unroll
            for (int r = 0; r < 4; ++r) {
                const int row = row_base + r;
                if (row < M)
                    out[(size_t)row * N_DIM + col] = acc[am][bn][r] + b_f;
            }
        }
    }
#undef LOAD_TILE
#undef WRITE_TILE
}

extern "C" void kernel_launch(void* const* d_in, const int* in_sizes, int n_in,
                              void* d_out, int out_size, void* d_ws, size_t ws_size,
                              hipStream_t stream) {
    const float* x    = (const float*)d_in[0];
    const int*   qw   = (const int*)d_in[1];
    const int*   qz   = (const int*)d_in[2];
    const float* sc   = (const float*)d_in[3];
    const float* bias = (const float*)d_in[4];
    float*       out  = (float*)d_out;

    const int M = in_sizes[0] / K_DIM;   // 2048 tokens
    dim3 grid(N_DIM / BN, (M + BM - 1) / BM);   // 43 x 16

    const size_t need = (size_t)M * K_DIM * 2;
    if (ws_size >= need) {
        ushort* xf = (ushort*)d_ws;
        int n8 = (M * K_DIM) / 8;
        cvt_x_kernel<<<dim3(2048), dim3(256), 0, stream>>>(x, xf, n8);
        awq_gemm_kernel<true><<<grid, dim3(256), 0, stream>>>(xf, qw, qz, sc, bias, out, M);
    } else {
        awq_gemm_kernel<false><<<grid, dim3(256), 0, stream>>>(x, qw, qz, sc, bias, out, M);
    }
}